// Round 10
// baseline (159.865 us; speedup 1.0000x reference)
//
#include <hip/hip_runtime.h>
#include <stdint.h>

// Problem constants (fixed by reference): b=8, CH=256, hw=64*64=4096, d_qk=32.
constexpr int CHN = 256;
constexpr int HW  = 4096;

// fp8 V blob geometry: 64 keys/tile, rows of 64 data bytes + 8 pad = 72B
// (bank index 18*l5 mod 32 -> distinct per 16 lanes => <=2-way, free per m136;
//  72 = 8*9 keeps every b64 read 8B-aligned). Tile = 256ch * 72B = 18432B.
constexpr int VROW  = 72;
constexpr int VTILE = 256 * VROW;          // 18432 = 18 KiB-chunks of 1024
constexpr int VBATCH = 64 * VTILE;

typedef float f32x4   __attribute__((ext_vector_type(4)));
typedef float f32x16  __attribute__((ext_vector_type(16)));
typedef short bf16x8  __attribute__((ext_vector_type(8)));
typedef short s16x4   __attribute__((ext_vector_type(4)));

static __device__ __forceinline__ short f2bf(float f) {
  uint32_t u = __builtin_bit_cast(uint32_t, f);
  u += 0x7FFFu + ((u >> 16) & 1u);   // RNE
  return (short)(u >> 16);
}

static __device__ __forceinline__ uint8_t f2fp8(float f) {
  return (uint8_t)__builtin_amdgcn_cvt_pk_fp8_f32(f, f, 0, false);
}

// async global->LDS, 16B per lane; LDS dest wave-uniform base (HW adds lane*16)
static __device__ __forceinline__ void gl16(const void* g, void* l) {
  __builtin_amdgcn_global_load_lds(
      (const __attribute__((address_space(1))) uint32_t*)g,
      (__attribute__((address_space(3))) uint32_t*)l, 16, 0, 0);
}

// ---- prep: Wb[320][256] bf16 = concat(Wv, Wq, Wk); bcat[320] f32 ----
__global__ __launch_bounds__(256) void prep_kernel(
    const float* __restrict__ Wq, const float* __restrict__ Wk, const float* __restrict__ Wv,
    const float* __restrict__ bq, const float* __restrict__ bk, const float* __restrict__ bv,
    short* __restrict__ Wb, float* __restrict__ bcat) {
  int idx = blockIdx.x * 256 + threadIdx.x;
  if (idx < 320 * 256) {
    int r = idx >> 8, c = idx & 255;
    float w = (r < 256) ? Wv[idx]
            : (r < 288) ? Wq[(r - 256) * 256 + c]
                        : Wk[(r - 288) * 256 + c];
    Wb[idx] = f2bf(w);
  }
  if (idx < 320)
    bcat[idx] = (idx < 256) ? bv[idx] : (idx < 288) ? bq[idx - 256] : bk[idx - 288];
}

// ---- proj: qkv = Wb @ x + b via bf16 MFMA, LDS-free (R3 skeleton) ----
// V emitted as fp8 e4m3 per 64-col tile blob [c][72B], PV-permuted
// (byte pos = 16j + phi, no XOR swizzle; stride-72 provides bank spread).
// Q pre-scaled by log2(e) for exp2 softmax.
__global__ __launch_bounds__(320) void proj_kernel(
    const float* __restrict__ x, const short* __restrict__ Wb, const float* __restrict__ bcat,
    short* __restrict__ qw, short* __restrict__ kw, uint8_t* __restrict__ v8) {
  const int t    = threadIdx.x;
  const int b    = blockIdx.y;
  const int n0   = blockIdx.x * 64;
  const int lane = t & 63;
  const int w    = t >> 6;
  const int ln   = lane & 15;
  const int gp   = lane >> 4;

  const float* xb  = x + (size_t)b * CHN * HW + n0;
  const short* wbp = Wb + (w * 64 + ln) * 256 + gp * 8;

  const f32x4 zv = {0.f, 0.f, 0.f, 0.f};
  f32x4 acc[4][4];
#pragma unroll
  for (int i = 0; i < 4; ++i)
#pragma unroll
    for (int j = 0; j < 4; ++j) acc[i][j] = zv;

#pragma unroll 2
  for (int ks = 0; ks < 8; ++ks) {
    const int k0 = ks * 32;
    bf16x8 a[4];
#pragma unroll
    for (int i = 0; i < 4; ++i)
      a[i] = *(const bf16x8*)(wbp + i * 16 * 256 + k0);
    bf16x8 bxv[4];
#pragma unroll
    for (int j = 0; j < 4; ++j) {
      const float* xc = xb + (size_t)(k0 + gp * 8) * HW + 16 * j + ln;
#pragma unroll
      for (int e = 0; e < 8; ++e) bxv[j][e] = f2bf(xc[(size_t)e * HW]);
    }
#pragma unroll
    for (int i = 0; i < 4; ++i)
#pragma unroll
      for (int j = 0; j < 4; ++j)
        acc[i][j] = __builtin_amdgcn_mfma_f32_16x16x32_bf16(a[i], bxv[j], acc[i][j], 0, 0, 0);
  }

  if (w < 4) {   // V rows -> fp8 blob [b][tile][c][pos], row stride 72B
    uint8_t* vblob = v8 + ((size_t)(b * 64 + blockIdx.x)) * VTILE;
    const int phi = 8 * ((ln >> 2) & 1) + 4 * (ln >> 3) + (ln & 3);
#pragma unroll
    for (int i = 0; i < 4; ++i) {
#pragma unroll
      for (int r = 0; r < 4; ++r) {
        const int c = w * 64 + 16 * i + 4 * gp + r;
        const float bias = bcat[c];
#pragma unroll
        for (int j = 0; j < 4; ++j)
          vblob[c * VROW + 16 * j + phi] = f2fp8(acc[i][j][r] + bias);
      }
    }
  } else {       // w == 4: i 0,1 -> Q rows (x log2e); i 2,3 -> K rows; [b][n][32]
    constexpr float LOG2E = 1.44269504088896340736f;
#pragma unroll
    for (int j = 0; j < 4; ++j) {
      const size_t nrow = ((size_t)b * HW + n0 + 16 * j + ln) * 32;
#pragma unroll
      for (int i = 0; i < 2; ++i) {
        s16x4 pq, pk;
#pragma unroll
        for (int r = 0; r < 4; ++r) {
          pq[r] = f2bf((acc[i][j][r] + bcat[256 + 16 * i + 4 * gp + r]) * LOG2E);
          pk[r] = f2bf(acc[i + 2][j][r] + bcat[288 + 16 * i + 4 * gp + r]);
        }
        *(s16x4*)(qw + nrow + 16 * i + 4 * gp) = pq;
        *(s16x4*)(kw + nrow + 16 * i + 4 * gp) = pk;
      }
    }
  }
}

// ---- fused flash attention + residual (R3 structure: 4 waves, 128 q/block) ----
// Changes vs R3: fp8 PV (b64 V frags, stride-72 rows, cvt_pk_fp8 P packing) and
// counted-vmcnt raw barrier (T4): kf prefetch (4 loads) is always the newest
// vmem, so vmcnt(4) drains exactly the current tile's staging chunks while
// next-tile chunks stay in flight. "memory" asm fences pin the issue order.
__global__ __launch_bounds__(256, 1) void attn_kernel(
    const float* __restrict__ x, const float* __restrict__ gamma,
    const short* __restrict__ qw, const short* __restrict__ kw,
    const uint8_t* __restrict__ v8, float* __restrict__ out) {
  __shared__ alignas(16) char sm[2 * VTILE];   // 36864 B; epilogue overlay fits

  const int tid  = threadIdx.x;
  const int lane = tid & 63;
  const int wv   = tid >> 6;
  const int l5   = lane & 31;
  const int h    = lane >> 5;
  const int b    = blockIdx.x & 7;
  const int qt   = blockIdx.x >> 3;
  const int qbase = qt * 128;

  const short*   qb    = qw + (size_t)b * HW * 32;
  const short*   kb    = kw + (size_t)b * HW * 32;
  const uint8_t* vblob = v8 + (size_t)b * VBATCH;

  // Q fragments (B-operand): q = qbase + wv*32 + l5; k-chunks {0,16}+h*8
  const short* qrow = qb + (size_t)(qbase + wv * 32 + l5) * 32 + h * 8;
  const bf16x8 qf0 = *(const bf16x8*)(qrow);
  const bf16x8 qf1 = *(const bf16x8*)(qrow + 16);

  f32x16 z16;
#pragma unroll
  for (int r = 0; r < 16; ++r) z16[r] = 0.f;
  f32x16 O[8];
#pragma unroll
  for (int ct = 0; ct < 8; ++ct) O[ct] = z16;
  float mrun = -1e30f, lrun = 0.f;

  // stage one tile (18 chunks of 1024B interleaved across 4 waves: 5/5/4/4)
  auto stage = [&](int tile, char* lbuf) {
    const uint8_t* gt = vblob + (size_t)tile * VTILE;
#pragma unroll
    for (int j = 0; j < 5; ++j) {
      const int cidx = wv + 4 * j;               // wave-uniform
      if (cidx < 18)
        gl16(gt + cidx * 1024 + lane * 16, lbuf + cidx * 1024);
    }
  };

  // prologue: stage tile 0, then kf(0) loads (order pinned by fence)
  stage(0, sm);
  asm volatile("" ::: "memory");
  const short* kfb = kb + (size_t)l5 * 32 + h * 8;
  bf16x8 kf00 = *(const bf16x8*)(kfb);
  bf16x8 kf01 = *(const bf16x8*)(kfb + 16);
  bf16x8 kf10 = *(const bf16x8*)(kfb + 1024);
  bf16x8 kf11 = *(const bf16x8*)(kfb + 1024 + 16);

  for (int it = 0; it < 64; ++it) {
    // tile(it) chunks complete (only kf may remain in flight), then barrier
    asm volatile("s_waitcnt vmcnt(4)" ::: "memory");
    __builtin_amdgcn_s_barrier();
    asm volatile("" ::: "memory");

    const char* buf = sm + (it & 1) * VTILE;
    if (it < 63) stage(it + 1, sm + ((it + 1) & 1) * VTILE);
    asm volatile("" ::: "memory");   // keep gl16 older than kf prefetch below

    // QK^T: S^T[m][q], two 32-m tiles, d=32 in two k-chunks
    f32x16 s0 = __builtin_amdgcn_mfma_f32_32x32x16_bf16(kf00, qf0, z16, 0, 0, 0);
    s0 = __builtin_amdgcn_mfma_f32_32x32x16_bf16(kf01, qf1, s0, 0, 0, 0);
    f32x16 s1 = __builtin_amdgcn_mfma_f32_32x32x16_bf16(kf10, qf0, z16, 0, 0, 0);
    s1 = __builtin_amdgcn_mfma_f32_32x32x16_bf16(kf11, qf1, s1, 0, 0, 0);

    if (it < 63) {                 // prefetch next iter's K frags (newest 4 vmem)
      const short* kn = kfb + (size_t)(it + 1) * 2048;
      kf00 = *(const bf16x8*)(kn);
      kf01 = *(const bf16x8*)(kn + 16);
      kf10 = *(const bf16x8*)(kn + 1024);
      kf11 = *(const bf16x8*)(kn + 1024 + 16);
    }

    // online softmax in log2 space (Q pre-scaled by log2e), defer-max thr=8
    float tmax = -1e30f;
#pragma unroll
    for (int r = 0; r < 16; ++r) tmax = fmaxf(tmax, fmaxf(s0[r], s1[r]));
    tmax = fmaxf(tmax, __shfl_xor(tmax, 32));
    if (__any(tmax > mrun + 8.f)) {
      const float mnew = fmaxf(mrun, tmax);
      const float al = __builtin_amdgcn_exp2f(mrun - mnew);
      lrun *= al;
      mrun = mnew;
#pragma unroll
      for (int r = 0; r < 16; ++r) {
        const float ar = __shfl(al, (r & 3) + 8 * (r >> 2) + 4 * h);
#pragma unroll
        for (int ct = 0; ct < 8; ++ct) O[ct][r] *= ar;
      }
    }
    float ps = 0.f;
#pragma unroll
    for (int r = 0; r < 16; ++r) {
      s0[r] = __builtin_amdgcn_exp2f(s0[r] - mrun);
      s1[r] = __builtin_amdgcn_exp2f(s1[r] - mrun);
      ps += s0[r] + s1[r];
    }
    ps += __shfl_xor(ps, 32);
    lrun += ps;

    // PV fp8: 4 m-chunks x 8 c-tiles; P packed in-reg (byte e = s[r0+e]),
    // V b64 from stride-72 LDS rows (channel ct*32+l5 at ct*2304 + l5*72)
    const char* vbl = buf + l5 * VROW;
#pragma unroll
    for (int mt = 0; mt < 4; ++mt) {
      const int r0 = (mt & 1) * 8;
      int lo, hi;
      if (mt < 2) {
        lo = __builtin_amdgcn_cvt_pk_fp8_f32(s0[r0 + 0], s0[r0 + 1], 0,  false);
        lo = __builtin_amdgcn_cvt_pk_fp8_f32(s0[r0 + 2], s0[r0 + 3], lo, true);
        hi = __builtin_amdgcn_cvt_pk_fp8_f32(s0[r0 + 4], s0[r0 + 5], 0,  false);
        hi = __builtin_amdgcn_cvt_pk_fp8_f32(s0[r0 + 6], s0[r0 + 7], hi, true);
      } else {
        lo = __builtin_amdgcn_cvt_pk_fp8_f32(s1[r0 + 0], s1[r0 + 1], 0,  false);
        lo = __builtin_amdgcn_cvt_pk_fp8_f32(s1[r0 + 2], s1[r0 + 3], lo, true);
        hi = __builtin_amdgcn_cvt_pk_fp8_f32(s1[r0 + 4], s1[r0 + 5], 0,  false);
        hi = __builtin_amdgcn_cvt_pk_fp8_f32(s1[r0 + 6], s1[r0 + 7], hi, true);
      }
      const long long pa = (long long)(((uint64_t)(uint32_t)hi << 32) | (uint32_t)lo);
      const int vo = 16 * mt + 8 * h;
#pragma unroll
      for (int ct = 0; ct < 8; ++ct) {
        const long long vf = *(const long long*)(vbl + ct * (32 * VROW) + vo);
        O[ct] = __builtin_amdgcn_mfma_f32_32x32x16_fp8_fp8(pa, vf, O[ct], 0, 0, 0);
      }
    }
  }

  // epilogue: fold gamma/l, transpose via LDS, coalesced residual-add store
  const float g0 = gamma[0];
  float linv[16];
#pragma unroll
  for (int r = 0; r < 16; ++r)
    linv[r] = g0 / __shfl(lrun, (r & 3) + 8 * (r >> 2) + 4 * h);

  float* eo = (float*)sm;   // [32 c][132 q-stride] overlay (16896 B < 36864)
  for (int ct = 0; ct < 8; ++ct) {
    __syncthreads();
#pragma unroll
    for (int r = 0; r < 16; ++r)
      eo[l5 * 132 + wv * 32 + ((r & 3) + 8 * (r >> 2) + 4 * h)] = O[ct][r] * linv[r];
    __syncthreads();
    const int cl = tid >> 3, seg = tid & 7;
    const size_t gi = ((size_t)b * CHN + ct * 32 + cl) * HW + qbase + seg * 16;
#pragma unroll
    for (int u = 0; u < 4; ++u) {
      const f32x4 xv = *(const f32x4*)(x + gi + u * 4);
      const f32x4 ov = *(const f32x4*)(&eo[cl * 132 + seg * 16 + u * 4]);
      *(f32x4*)(out + gi + u * 4) = xv + ov;
    }
  }
}

extern "C" void kernel_launch(void* const* d_in, const int* in_sizes, int n_in,
                              void* d_out, int out_size, void* d_ws, size_t ws_size,
                              hipStream_t stream) {
  const float* x     = (const float*)d_in[0];
  const float* Wq    = (const float*)d_in[1];
  const float* bq    = (const float*)d_in[2];
  const float* Wk    = (const float*)d_in[3];
  const float* bk    = (const float*)d_in[4];
  const float* Wv    = (const float*)d_in[5];
  const float* bv    = (const float*)d_in[6];
  const float* gamma = (const float*)d_in[7];
  float* out = (float*)d_out;

  // workspace: Q 2MB | K 2MB | V fp8 blobs ~9MB | Wb bf16 160KB | bcat
  char* ws = (char*)d_ws;
  short*   qw   = (short*)(ws);
  short*   kw   = (short*)(ws + (2u << 20));
  uint8_t* v8   = (uint8_t*)(ws + (4u << 20));
  short*   Wb   = (short*)(ws + (20u << 20));
  float*   bcat = (float*)(ws + (20u << 20) + (256u << 10));

  prep_kernel<<<320, 256, 0, stream>>>(Wq, Wk, Wv, bq, bk, bv, Wb, bcat);
  proj_kernel<<<dim3(64, 8), 320, 0, stream>>>(x, Wb, bcat, qw, kw, v8);
  attn_kernel<<<256, 256, 0, stream>>>(x, gamma, qw, kw, v8, out);
}

// Round 11
// 132.857 us; speedup vs baseline: 1.2033x; 1.2033x over previous
//
#include <hip/hip_runtime.h>
#include <stdint.h>

// Problem constants (fixed by reference): b=8, CH=256, hw=64*64=4096, d_qk=32.
constexpr int CHN = 256;
constexpr int HW  = 4096;

// fp8 V blob geometry: 64 keys/tile, rows of 64 data bytes + 8 pad = 72B
// (bank index 18*l5 mod 32 -> distinct per 16 lanes => <=2-way, free per m136;
//  72 = 8*9 keeps every b64 read 8B-aligned). Tile = 256ch * 72B = 18432B.
constexpr int VROW   = 72;
constexpr int VTILE  = 256 * VROW;         // full tile blob (proj writes this)
constexpr int HTILE  = 128 * VROW;         // 9216B = one channel half (attn stages this)
constexpr int VBATCH = 64 * VTILE;

typedef float f32x4   __attribute__((ext_vector_type(4)));
typedef float f32x16  __attribute__((ext_vector_type(16)));
typedef short bf16x8  __attribute__((ext_vector_type(8)));
typedef short s16x4   __attribute__((ext_vector_type(4)));

static __device__ __forceinline__ short f2bf(float f) {
  uint32_t u = __builtin_bit_cast(uint32_t, f);
  u += 0x7FFFu + ((u >> 16) & 1u);   // RNE
  return (short)(u >> 16);
}

static __device__ __forceinline__ uint8_t f2fp8(float f) {
  return (uint8_t)__builtin_amdgcn_cvt_pk_fp8_f32(f, f, 0, false);
}

// async global->LDS, 16B per lane; LDS dest wave-uniform base (HW adds lane*16)
static __device__ __forceinline__ void gl16(const void* g, void* l) {
  __builtin_amdgcn_global_load_lds(
      (const __attribute__((address_space(1))) uint32_t*)g,
      (__attribute__((address_space(3))) uint32_t*)l, 16, 0, 0);
}

// ---- prep: Wb[320][256] bf16 = concat(Wv, Wq, Wk); bcat[320] f32 ----
__global__ __launch_bounds__(256) void prep_kernel(
    const float* __restrict__ Wq, const float* __restrict__ Wk, const float* __restrict__ Wv,
    const float* __restrict__ bq, const float* __restrict__ bk, const float* __restrict__ bv,
    short* __restrict__ Wb, float* __restrict__ bcat) {
  int idx = blockIdx.x * 256 + threadIdx.x;
  if (idx < 320 * 256) {
    int r = idx >> 8, c = idx & 255;
    float w = (r < 256) ? Wv[idx]
            : (r < 288) ? Wq[(r - 256) * 256 + c]
                        : Wk[(r - 288) * 256 + c];
    Wb[idx] = f2bf(w);
  }
  if (idx < 320)
    bcat[idx] = (idx < 256) ? bv[idx] : (idx < 288) ? bq[idx - 256] : bk[idx - 288];
}

// ---- proj: qkv = Wb @ x + b via bf16 MFMA, LDS-free (verbatim R10, proven) ----
__global__ __launch_bounds__(320) void proj_kernel(
    const float* __restrict__ x, const short* __restrict__ Wb, const float* __restrict__ bcat,
    short* __restrict__ qw, short* __restrict__ kw, uint8_t* __restrict__ v8) {
  const int t    = threadIdx.x;
  const int b    = blockIdx.y;
  const int n0   = blockIdx.x * 64;
  const int lane = t & 63;
  const int w    = t >> 6;
  const int ln   = lane & 15;
  const int gp   = lane >> 4;

  const float* xb  = x + (size_t)b * CHN * HW + n0;
  const short* wbp = Wb + (w * 64 + ln) * 256 + gp * 8;

  const f32x4 zv = {0.f, 0.f, 0.f, 0.f};
  f32x4 acc[4][4];
#pragma unroll
  for (int i = 0; i < 4; ++i)
#pragma unroll
    for (int j = 0; j < 4; ++j) acc[i][j] = zv;

#pragma unroll 2
  for (int ks = 0; ks < 8; ++ks) {
    const int k0 = ks * 32;
    bf16x8 a[4];
#pragma unroll
    for (int i = 0; i < 4; ++i)
      a[i] = *(const bf16x8*)(wbp + i * 16 * 256 + k0);
    bf16x8 bxv[4];
#pragma unroll
    for (int j = 0; j < 4; ++j) {
      const float* xc = xb + (size_t)(k0 + gp * 8) * HW + 16 * j + ln;
#pragma unroll
      for (int e = 0; e < 8; ++e) bxv[j][e] = f2bf(xc[(size_t)e * HW]);
    }
#pragma unroll
    for (int i = 0; i < 4; ++i)
#pragma unroll
      for (int j = 0; j < 4; ++j)
        acc[i][j] = __builtin_amdgcn_mfma_f32_16x16x32_bf16(a[i], bxv[j], acc[i][j], 0, 0, 0);
  }

  if (w < 4) {   // V rows -> fp8 blob [b][tile][c][pos], row stride 72B
    uint8_t* vblob = v8 + ((size_t)(b * 64 + blockIdx.x)) * VTILE;
    const int phi = 8 * ((ln >> 2) & 1) + 4 * (ln >> 3) + (ln & 3);
#pragma unroll
    for (int i = 0; i < 4; ++i) {
#pragma unroll
      for (int r = 0; r < 4; ++r) {
        const int c = w * 64 + 16 * i + 4 * gp + r;
        const float bias = bcat[c];
#pragma unroll
        for (int j = 0; j < 4; ++j)
          vblob[c * VROW + 16 * j + phi] = f2fp8(acc[i][j][r] + bias);
      }
    }
  } else {       // w == 4: i 0,1 -> Q rows (x log2e); i 2,3 -> K rows; [b][n][32]
    constexpr float LOG2E = 1.44269504088896340736f;
#pragma unroll
    for (int j = 0; j < 4; ++j) {
      const size_t nrow = ((size_t)b * HW + n0 + 16 * j + ln) * 32;
#pragma unroll
      for (int i = 0; i < 2; ++i) {
        s16x4 pq, pk;
#pragma unroll
        for (int r = 0; r < 4; ++r) {
          pq[r] = f2bf((acc[i][j][r] + bcat[256 + 16 * i + 4 * gp + r]) * LOG2E);
          pk[r] = f2bf(acc[i + 2][j][r] + bcat[288 + 16 * i + 4 * gp + r]);
        }
        *(s16x4*)(qw + nrow + 16 * i + 4 * gp) = pq;
        *(s16x4*)(kw + nrow + 16 * i + 4 * gp) = pk;
      }
    }
  }
}

// ---- fused flash attention + residual, c-split across blocks ----
// Grid 512: block (b = bid&7, g = (bid>>3)&1, qt = bid>>4). Same 128 q-rows as
// R10 but only channel half [g*128, +128): half-tile staging (9KB), PV ct<4,
// O[4]. QK^T+softmax duplicated across the g-pair (VALU cost, accepted) so no
// cross-block coupling. Sync/staging discipline byte-identical to green R10.
__global__ __launch_bounds__(256, 2) void attn_kernel(
    const float* __restrict__ x, const float* __restrict__ gamma,
    const short* __restrict__ qw, const short* __restrict__ kw,
    const uint8_t* __restrict__ v8, float* __restrict__ out) {
  __shared__ alignas(16) char sm[2 * HTILE];   // 18432 B; epilogue overlay fits

  const int tid  = threadIdx.x;
  const int lane = tid & 63;
  const int wv   = tid >> 6;
  const int l5   = lane & 31;
  const int h    = lane >> 5;
  const int b    = blockIdx.x & 7;
  const int g    = (blockIdx.x >> 3) & 1;
  const int qt   = blockIdx.x >> 4;
  const int qbase = qt * 128;

  const short*   qb    = qw + (size_t)b * HW * 32;
  const short*   kb    = kw + (size_t)b * HW * 32;
  const uint8_t* vblob = v8 + (size_t)b * VBATCH + (size_t)g * HTILE;  // channel half

  // Q fragments (B-operand): q = qbase + wv*32 + l5; k-chunks {0,16}+h*8
  const short* qrow = qb + (size_t)(qbase + wv * 32 + l5) * 32 + h * 8;
  const bf16x8 qf0 = *(const bf16x8*)(qrow);
  const bf16x8 qf1 = *(const bf16x8*)(qrow + 16);

  f32x16 z16;
#pragma unroll
  for (int r = 0; r < 16; ++r) z16[r] = 0.f;
  f32x16 O[4];
#pragma unroll
  for (int ct = 0; ct < 4; ++ct) O[ct] = z16;
  float mrun = -1e30f, lrun = 0.f;

  // stage one half-tile (9 chunks of 1024B spread over 4 waves: 3/2/2/2)
  auto stage = [&](int tile, char* lbuf) {
    const uint8_t* gt = vblob + (size_t)tile * VTILE;
#pragma unroll
    for (int j = 0; j < 3; ++j) {
      const int cidx = wv + 4 * j;               // wave-uniform
      if (cidx < 9)
        gl16(gt + cidx * 1024 + lane * 16, lbuf + cidx * 1024);
    }
  };

  // prologue: stage tile 0, then kf(0) loads (order pinned by fence)
  stage(0, sm);
  asm volatile("" ::: "memory");
  const short* kfb = kb + (size_t)l5 * 32 + h * 8;
  bf16x8 kf00 = *(const bf16x8*)(kfb);
  bf16x8 kf01 = *(const bf16x8*)(kfb + 16);
  bf16x8 kf10 = *(const bf16x8*)(kfb + 1024);
  bf16x8 kf11 = *(const bf16x8*)(kfb + 1024 + 16);

  for (int it = 0; it < 64; ++it) {
    // tile(it) chunks complete (only the 4 kf loads may remain), then barrier
    asm volatile("s_waitcnt vmcnt(4)" ::: "memory");
    __builtin_amdgcn_s_barrier();
    asm volatile("" ::: "memory");

    const char* buf = sm + (it & 1) * HTILE;
    if (it < 63) stage(it + 1, sm + ((it + 1) & 1) * HTILE);
    asm volatile("" ::: "memory");   // keep gl16 older than kf prefetch below

    // QK^T: S^T[m][q], two 32-m tiles, d=32 in two k-chunks
    f32x16 s0 = __builtin_amdgcn_mfma_f32_32x32x16_bf16(kf00, qf0, z16, 0, 0, 0);
    s0 = __builtin_amdgcn_mfma_f32_32x32x16_bf16(kf01, qf1, s0, 0, 0, 0);
    f32x16 s1 = __builtin_amdgcn_mfma_f32_32x32x16_bf16(kf10, qf0, z16, 0, 0, 0);
    s1 = __builtin_amdgcn_mfma_f32_32x32x16_bf16(kf11, qf1, s1, 0, 0, 0);

    if (it < 63) {                 // prefetch next iter's K frags (newest 4 vmem)
      const short* kn = kfb + (size_t)(it + 1) * 2048;
      kf00 = *(const bf16x8*)(kn);
      kf01 = *(const bf16x8*)(kn + 16);
      kf10 = *(const bf16x8*)(kn + 1024);
      kf11 = *(const bf16x8*)(kn + 1024 + 16);
    }

    // online softmax in log2 space (Q pre-scaled by log2e), defer-max thr=8.
    // Tree reduce (depth 5) instead of a depth-32 linear chain.
    float tm[8];
#pragma unroll
    for (int r = 0; r < 8; ++r)
      tm[r] = fmaxf(fmaxf(s0[r], s0[r + 8]), fmaxf(s1[r], s1[r + 8]));
#pragma unroll
    for (int r = 0; r < 4; ++r) tm[r] = fmaxf(tm[r], tm[r + 4]);
    float tmax = fmaxf(fmaxf(tm[0], tm[2]), fmaxf(tm[1], tm[3]));
    tmax = fmaxf(tmax, __shfl_xor(tmax, 32));
    if (__any(tmax > mrun + 8.f)) {
      const float mnew = fmaxf(mrun, tmax);
      const float al = __builtin_amdgcn_exp2f(mrun - mnew);
      lrun *= al;
      mrun = mnew;
#pragma unroll
      for (int r = 0; r < 16; ++r) {
        const float ar = __shfl(al, (r & 3) + 8 * (r >> 2) + 4 * h);
#pragma unroll
        for (int ct = 0; ct < 4; ++ct) O[ct][r] *= ar;
      }
    }
#pragma unroll
    for (int r = 0; r < 16; ++r) {
      s0[r] = __builtin_amdgcn_exp2f(s0[r] - mrun);
      s1[r] = __builtin_amdgcn_exp2f(s1[r] - mrun);
    }
    float pp[8];
#pragma unroll
    for (int r = 0; r < 8; ++r)
      pp[r] = (s0[r] + s0[r + 8]) + (s1[r] + s1[r + 8]);
#pragma unroll
    for (int r = 0; r < 4; ++r) pp[r] += pp[r + 4];
    float ps = (pp[0] + pp[2]) + (pp[1] + pp[3]);
    ps += __shfl_xor(ps, 32);
    lrun += ps;

    // PV fp8: 4 m-chunks x 4 c-tiles (this block's 128 channels)
    const char* vbl = buf + l5 * VROW;
#pragma unroll
    for (int mt = 0; mt < 4; ++mt) {
      const int r0 = (mt & 1) * 8;
      int lo, hi;
      if (mt < 2) {
        lo = __builtin_amdgcn_cvt_pk_fp8_f32(s0[r0 + 0], s0[r0 + 1], 0,  false);
        lo = __builtin_amdgcn_cvt_pk_fp8_f32(s0[r0 + 2], s0[r0 + 3], lo, true);
        hi = __builtin_amdgcn_cvt_pk_fp8_f32(s0[r0 + 4], s0[r0 + 5], 0,  false);
        hi = __builtin_amdgcn_cvt_pk_fp8_f32(s0[r0 + 6], s0[r0 + 7], hi, true);
      } else {
        lo = __builtin_amdgcn_cvt_pk_fp8_f32(s1[r0 + 0], s1[r0 + 1], 0,  false);
        lo = __builtin_amdgcn_cvt_pk_fp8_f32(s1[r0 + 2], s1[r0 + 3], lo, true);
        hi = __builtin_amdgcn_cvt_pk_fp8_f32(s1[r0 + 4], s1[r0 + 5], 0,  false);
        hi = __builtin_amdgcn_cvt_pk_fp8_f32(s1[r0 + 6], s1[r0 + 7], hi, true);
      }
      const long long pa = (long long)(((uint64_t)(uint32_t)hi << 32) | (uint32_t)lo);
      const int vo = 16 * mt + 8 * h;
#pragma unroll
      for (int ct = 0; ct < 4; ++ct) {
        const long long vf = *(const long long*)(vbl + ct * (32 * VROW) + vo);
        O[ct] = __builtin_amdgcn_mfma_f32_32x32x16_fp8_fp8(pa, vf, O[ct], 0, 0, 0);
      }
    }
  }

  // epilogue: fold gamma/l, transpose via LDS, coalesced residual-add store
  const float g0 = gamma[0];
  float linv[16];
#pragma unroll
  for (int r = 0; r < 16; ++r)
    linv[r] = g0 / __shfl(lrun, (r & 3) + 8 * (r >> 2) + 4 * h);

  float* eo = (float*)sm;   // [32 c][132 q-stride] overlay (16896 B < 18432)
  for (int ct = 0; ct < 4; ++ct) {
    __syncthreads();
#pragma unroll
    for (int r = 0; r < 16; ++r)
      eo[l5 * 132 + wv * 32 + ((r & 3) + 8 * (r >> 2) + 4 * h)] = O[ct][r] * linv[r];
    __syncthreads();
    const int cl = tid >> 3, seg = tid & 7;
    const size_t gi = ((size_t)b * CHN + g * 128 + ct * 32 + cl) * HW + qbase + seg * 16;
#pragma unroll
    for (int u = 0; u < 4; ++u) {
      const f32x4 xv = *(const f32x4*)(x + gi + u * 4);
      const f32x4 ov = *(const f32x4*)(&eo[cl * 132 + seg * 16 + u * 4]);
      *(f32x4*)(out + gi + u * 4) = xv + ov;
    }
  }
}

extern "C" void kernel_launch(void* const* d_in, const int* in_sizes, int n_in,
                              void* d_out, int out_size, void* d_ws, size_t ws_size,
                              hipStream_t stream) {
  const float* x     = (const float*)d_in[0];
  const float* Wq    = (const float*)d_in[1];
  const float* bq    = (const float*)d_in[2];
  const float* Wk    = (const float*)d_in[3];
  const float* bk    = (const float*)d_in[4];
  const float* Wv    = (const float*)d_in[5];
  const float* bv    = (const float*)d_in[6];
  const float* gamma = (const float*)d_in[7];
  float* out = (float*)d_out;

  // workspace: Q 2MB | K 2MB | V fp8 blobs ~9MB | Wb bf16 160KB | bcat
  char* ws = (char*)d_ws;
  short*   qw   = (short*)(ws);
  short*   kw   = (short*)(ws + (2u << 20));
  uint8_t* v8   = (uint8_t*)(ws + (4u << 20));
  short*   Wb   = (short*)(ws + (20u << 20));
  float*   bcat = (float*)(ws + (20u << 20) + (256u << 10));

  prep_kernel<<<320, 256, 0, stream>>>(Wq, Wk, Wv, bq, bk, bv, Wb, bcat);
  proj_kernel<<<dim3(64, 8), 320, 0, stream>>>(x, Wb, bcat, qw, kw, v8);
  attn_kernel<<<512, 256, 0, stream>>>(x, gamma, qw, kw, v8, out);
}